// Round 1
// baseline (807.675 us; speedup 1.0000x reference)
//
#include <hip/hip_runtime.h>
#include <hip/hip_bf16.h>

// MAMBA_BayesMAGAC: B=32, L=512, D=128, E=64, HS=64, DTR=4, U=32, R=3, K=3, DE=10, NH=4
// Full fp32 implementation. Round 0: correctness-first, layouts chosen for coalescing.

#define B_ 32
#define L_ 512
#define D_ 128
#define E_ 64
#define HS_ 64
#define BL_ (B_ * L_)   // 16384

// ---- workspace offsets (in floats) ----
// layer phase:
#define OFF_X    0u          // 2,097,152  current x [b][l][128]
#define OFF_XZF  2097152u    // 2,097,152  xz fwd [b][l][128] (0:64 xp_raw, 64:128 res)
#define OFF_XZB  4194304u
#define OFF_XPF  6291456u    // 1,048,576  xp post conv+silu [b][l][64]
#define OFF_XPB  7340032u
#define OFF_DLF  8388608u    // 1,048,576  delta [b][l][64]
#define OFF_DLB  9437184u
#define OFF_XDF  10485760u   // 2,162,688  xdbl [b][l][132]
#define OFF_XDB  12648448u
#define OFF_YSF  14811136u   // 1,048,576  scan y, TRANSPOSED [b][e][l]
#define OFF_YSB  15859712u
#define OFF_YGF  16908288u   // 1,048,576  gated y [b][l][64]
#define OFF_YGB  17956864u   // ends 19,005,440 floats = 76,021,760 bytes
// reuse (liveness-checked):
#define OFF_Y1   10485760u   // over XDF (dead after scan)
#define OFF_Y2   12648448u   // over XDB
#define OFF_Y3   14811136u   // over YSF+YSB (dead after gate)
#define OFF_HID  16908288u   // over YGF (dead after outproj)
// head phase (everything but OFF_X dead):
#define OFF_V    2097152u    // 8,388,608  V [l][m][n]
#define OFF_WFT  10485760u   // 1,048,576  Wf [h][k][l][n]
#define OFF_STT  11534336u   // 262,144    S^T [h][k][m][n]  (= S_k[n][m])
#define OFF_AEFF 11796480u   // 65,536
#define OFF_GB   11862016u   // 16,384
#define OFF_QKB  11878400u   // 65,536
#define OFF_QB   11943936u   // 5,120
#define OFF_KB   11949056u   // 5,120
#define OFF_MIX  11954176u   // 4
#define OFF_ALPH 11954180u   // 1
#define OFF_BFT  11954184u   // 128
#define OFF_PART 12582912u   // 2,097,152  partial [512][32][128]

__device__ __forceinline__ float sigf(float x) { return 1.f / (1.f + __expf(-x)); }

// ---------------- in-projection: xz = x @ in_w (both directions) ----------------
// grid 1024, block 256. 16 rows/block, K=128 chunked by 32, both W's staged.
__global__ __launch_bounds__(256) void gemm_in2_kernel(
    const float* __restrict__ X, const float* __restrict__ WF, const float* __restrict__ WB,
    float* __restrict__ xzF, float* __restrict__ xzB)
{
    __shared__ float sx[16][128];
    __shared__ float sw[2][32][128];
    const int tid = threadIdx.x;
    const int r0 = blockIdx.x * 16;
    for (int q = tid; q < 16 * 128; q += 256)
        sx[q >> 7][q & 127] = X[(r0 + (q >> 7)) * 128 + (q & 127)];
    const int wv = tid >> 6, lane = tid & 63;
    float acc[4][4];
#pragma unroll
    for (int r = 0; r < 4; ++r)
#pragma unroll
        for (int c = 0; c < 4; ++c) acc[r][c] = 0.f;
    for (int k0 = 0; k0 < 128; k0 += 32) {
        __syncthreads();
        for (int q = tid; q < 32 * 128; q += 256) {
            sw[0][q >> 7][q & 127] = WF[(k0 + (q >> 7)) * 128 + (q & 127)];
            sw[1][q >> 7][q & 127] = WB[(k0 + (q >> 7)) * 128 + (q & 127)];
        }
        __syncthreads();
#pragma unroll 8
        for (int kk = 0; kk < 32; ++kk) {
            const float wf0 = sw[0][kk][lane], wf1 = sw[0][kk][lane + 64];
            const float wb0 = sw[1][kk][lane], wb1 = sw[1][kk][lane + 64];
#pragma unroll
            for (int r = 0; r < 4; ++r) {
                const float xv = sx[wv * 4 + r][k0 + kk];
                acc[r][0] = fmaf(xv, wf0, acc[r][0]);
                acc[r][1] = fmaf(xv, wf1, acc[r][1]);
                acc[r][2] = fmaf(xv, wb0, acc[r][2]);
                acc[r][3] = fmaf(xv, wb1, acc[r][3]);
            }
        }
    }
#pragma unroll
    for (int r = 0; r < 4; ++r) {
        const int row = r0 + wv * 4 + r;
        xzF[row * 128 + lane]      = acc[r][0];
        xzF[row * 128 + lane + 64] = acc[r][1];
        xzB[row * 128 + lane]      = acc[r][2];
        xzB[row * 128 + lane + 64] = acc[r][3];
    }
}

// ------------- conv + silu + xproj + delta, both dirs. grid 8192, block 256 -------------
__global__ __launch_bounds__(256) void prep2_kernel(
    const float* __restrict__ xzF_, const float* __restrict__ xzB_,
    const float* __restrict__ conv_w, const float* __restrict__ conv_b,
    const float* __restrict__ xproj_w, const float* __restrict__ dt_w,
    const float* __restrict__ dt_b, int layer,
    float* __restrict__ xpF_, float* __restrict__ xpB_,
    float* __restrict__ xdF_, float* __restrict__ xdB_,
    float* __restrict__ dlF_, float* __restrict__ dlB_)
{
    __shared__ float sxp[4][64];
    __shared__ float sdl[4][4];
    const int tid = threadIdx.x, wv = tid >> 6, lane = tid & 63;
    const int wid = blockIdx.x * 4 + wv;          // 0..32767
    const int dir = wid >> 14;
    const int row = wid & 16383;
    const int b = row >> 9, l = row & 511;
    const int m = layer * 2 + dir;
    const float* xz = dir ? xzB_ : xzF_;
    float* xp = dir ? xpB_ : xpF_;
    float* xd = dir ? xdB_ : xdF_;
    float* dl = dir ? dlB_ : dlF_;
    // depthwise causal conv, e = lane. logical tau-2,tau-1,tau -> weights w0,w1,w2
    const float* cw = conv_w + m * 192 + lane * 3;
    const int l1 = dir ? l + 1 : l - 1;
    const int l2 = dir ? l + 2 : l - 2;
    float acc = conv_b[m * 64 + lane];
    const float x0 = xz[(b * 512 + l) * 128 + lane];
    const float x1 = (l1 >= 0 && l1 < 512) ? xz[(b * 512 + l1) * 128 + lane] : 0.f;
    const float x2 = (l2 >= 0 && l2 < 512) ? xz[(b * 512 + l2) * 128 + lane] : 0.f;
    acc += cw[0] * x2 + cw[1] * x1 + cw[2] * x0;
    const float u = acc * sigf(acc);   // silu
    xp[(b * 512 + l) * 64 + lane] = u;
    sxp[wv][lane] = u;
    __syncthreads();
    // xproj: row (64) @ W (64x132); lane covers cols lane, lane+64, 128+(lane&3)
    const float* W = xproj_w + m * 64 * 132;
    float a0 = 0.f, a1 = 0.f, a2 = 0.f;
    const int j2 = 128 + (lane & 3);
#pragma unroll 8
    for (int k = 0; k < 64; ++k) {
        const float xv = sxp[wv][k];
        a0 = fmaf(xv, W[k * 132 + lane], a0);
        a1 = fmaf(xv, W[k * 132 + lane + 64], a1);
        a2 = fmaf(xv, W[k * 132 + j2], a2);
    }
    const int rbase = (b * 512 + l) * 132;
    xd[rbase + lane] = a0;
    xd[rbase + 64 + lane] = a1;
    if (lane < 4) { xd[rbase + 128 + lane] = a2; sdl[wv][lane] = a0; }
    __syncthreads();
    // delta = softplus(xdbl[:,:4] @ dt_w + dt_b), e = lane
    float dpre = dt_b[m * 64 + lane];
    const float* dw = dt_w + m * 4 * 64;
#pragma unroll
    for (int r4 = 0; r4 < 4; ++r4) dpre = fmaf(sdl[wv][r4], dw[r4 * 64 + lane], dpre);
    const float dlt = (dpre > 20.f) ? dpre : log1pf(__expf(dpre));
    dl[(b * 512 + l) * 64 + lane] = dlt;
}

// ------------- selective scan, both dirs. grid 1024, block 256 (4 waves = 4 (b,e)) -------------
__global__ __launch_bounds__(256) void scan2_kernel(
    const float* __restrict__ xdF, const float* __restrict__ xdB,
    const float* __restrict__ dlF, const float* __restrict__ dlB,
    const float* __restrict__ xpF, const float* __restrict__ xpB,
    const float* __restrict__ AF, const float* __restrict__ AB,
    float* __restrict__ ysF, float* __restrict__ ysB)
{
    __shared__ float tile[4][32 * 65];
    const int wv = threadIdx.x >> 6, lane = threadIdx.x & 63;
    const int wid = blockIdx.x * 4 + wv;          // 0..4095
    const int dir = wid >> 11;
    const int be = wid & 2047;
    const int b = be >> 6, e = be & 63;
    const float* xd = dir ? xdB : xdF;
    const float* dl = dir ? dlB : dlF;
    const float* xp = dir ? xpB : xpF;
    const float* Aw = dir ? AB : AF;
    float* ys = dir ? ysB : ysF;
    const float a = -__expf(Aw[e * 64 + lane]);   // A[e][n], n = lane
    float s = 0.f;
    float* tl = tile[wv];
    for (int t0 = 0; t0 < 512; t0 += 32) {
        for (int tt = 0; tt < 32; ++tt) {
            const int tau = t0 + tt;
            const int l = dir ? (511 - tau) : tau;
            const int rowb = b * 512 + l;
            const float d_t = dl[rowb * 64 + e];
            const float u_t = xp[rowb * 64 + e];
            const float* xr = xd + rowb * 132;
            const float Bn = xr[4 + lane];
            const float Cn = xr[68 + lane];
            const float dA = __expf(d_t * a);
            s = fmaf(dA, s, d_t * Bn * u_t);
            tl[tt * 65 + lane] = s * Cn;
        }
        __syncthreads();
        const int tr = lane & 31, hf = lane >> 5;
        float p = 0.f;
#pragma unroll 8
        for (int j = 0; j < 32; ++j) p += tl[tr * 65 + hf * 32 + j];
        p += __shfl_xor(p, 32);
        if (lane < 32) {
            const int tau = t0 + tr;
            const int l = dir ? (511 - tau) : tau;
            ys[(b * 64 + e) * 512 + l] = p;
        }
        __syncthreads();
    }
}

// ------------- gate: y = (ys + xp*D) * sigmoid(res). grid 8192, block 256 -------------
__global__ __launch_bounds__(256) void gate2_kernel(
    const float* __restrict__ ysF_, const float* __restrict__ ysB_,
    const float* __restrict__ xpF_, const float* __restrict__ xpB_,
    const float* __restrict__ xzF_, const float* __restrict__ xzB_,
    const float* __restrict__ Dp, int layer,
    float* __restrict__ ygF_, float* __restrict__ ygB_)
{
    const int idx = blockIdx.x * 256 + threadIdx.x;  // < 2*2^20
    const int dir = idx >> 20;
    const int r = idx & 1048575;
    const int e = r & 63, bl = r >> 6;
    const int b = bl >> 9, l = bl & 511;
    const float* ys = dir ? ysB_ : ysF_;
    const float* xp = dir ? xpB_ : xpF_;
    const float* xz = dir ? xzB_ : xzF_;
    float* yg = dir ? ygB_ : ygF_;
    const float dv = Dp[(layer * 2 + dir) * 64 + e];
    const float y = ys[(b * 64 + e) * 512 + l];
    const float u = xp[bl * 64 + e];
    const float res = xz[bl * 128 + 64 + e];
    yg[bl * 64 + e] = (y + u * dv) * sigf(res);
}

// ------------- out-projection: Y = yg @ out_w. grid 2048, block 256 -------------
__global__ __launch_bounds__(256) void outproj2_kernel(
    const float* __restrict__ ygF_, const float* __restrict__ ygB_,
    const float* __restrict__ out_w, int layer,
    float* __restrict__ Y1, float* __restrict__ Y2)
{
    __shared__ float sy[16][64];
    __shared__ float sw[64][128];
    const int tid = threadIdx.x;
    const int dir = (int)(blockIdx.x >= 1024);
    const int r0 = (blockIdx.x & 1023) * 16;
    const float* yg = dir ? ygB_ : ygF_;
    float* Y = dir ? Y2 : Y1;
    const float* W = out_w + (layer * 2 + dir) * 64 * 128;
    for (int q = tid; q < 8192; q += 256) sw[q >> 7][q & 127] = W[q];
    for (int q = tid; q < 1024; q += 256) sy[q >> 6][q & 63] = yg[r0 * 64 + q];
    __syncthreads();
    const int wv = tid >> 6, lane = tid & 63;
    float acc[4][2];
#pragma unroll
    for (int r = 0; r < 4; ++r) { acc[r][0] = 0.f; acc[r][1] = 0.f; }
#pragma unroll 8
    for (int k = 0; k < 64; ++k) {
        const float w0 = sw[k][lane], w1 = sw[k][lane + 64];
#pragma unroll
        for (int r = 0; r < 4; ++r) {
            const float yv = sy[wv * 4 + r][k];
            acc[r][0] = fmaf(yv, w0, acc[r][0]);
            acc[r][1] = fmaf(yv, w1, acc[r][1]);
        }
    }
#pragma unroll
    for (int r = 0; r < 4; ++r) {
        const int row = r0 + wv * 4 + r;
        Y[row * 128 + lane]      = acc[r][0];
        Y[row * 128 + lane + 64] = acc[r][1];
    }
}

// ------------- LN(a+b+c). grid 4096, block 256 (wave per row) -------------
__global__ __launch_bounds__(256) void ln3_kernel(
    const float* __restrict__ A, const float* __restrict__ B1, const float* __restrict__ C1,
    const float* __restrict__ g, const float* __restrict__ bb, float* __restrict__ out)
{
    const int wv = threadIdx.x >> 6, lane = threadIdx.x & 63;
    const int base = (blockIdx.x * 4 + wv) * 128;
    const float v0 = A[base + lane] + B1[base + lane] + C1[base + lane];
    const float v1 = A[base + lane + 64] + B1[base + lane + 64] + C1[base + lane + 64];
    float sum = v0 + v1, sq = v0 * v0 + v1 * v1;
#pragma unroll
    for (int o = 32; o >= 1; o >>= 1) { sum += __shfl_xor(sum, o); sq += __shfl_xor(sq, o); }
    const float mean = sum * (1.f / 128.f);
    const float var = sq * (1.f / 128.f) - mean * mean;
    const float rs = rsqrtf(var + 1e-5f);
    out[base + lane]      = (v0 - mean) * rs * g[lane] + bb[lane];
    out[base + lane + 64] = (v1 - mean) * rs * g[lane + 64] + bb[lane + 64];
}

// ------------- FFN1: hid = relu(Y3@W1 + b1). grid 2048, block 256 (8 rows) -------------
__global__ __launch_bounds__(256) void ffn1_kernel(
    const float* __restrict__ Y3, const float* __restrict__ W1, const float* __restrict__ b1,
    float* __restrict__ hid)
{
    __shared__ float sx[8][128];
    const int tid = threadIdx.x;
    const int r0 = blockIdx.x * 8;
    for (int q = tid; q < 1024; q += 256)
        sx[q >> 7][q & 127] = Y3[(r0 + (q >> 7)) * 128 + (q & 127)];
    __syncthreads();
    const int wv = tid >> 6, lane = tid & 63;
    const int rloc = wv * 2 + (lane >> 5), u = lane & 31;
    float acc = b1[u];
#pragma unroll 8
    for (int k = 0; k < 128; ++k) acc = fmaf(sx[rloc][k], W1[k * 32 + u], acc);
    hid[(r0 + rloc) * 32 + u] = fmaxf(acc, 0.f);
}

// ------------- FFN2 + residual + LN2 -> x. grid 4096, block 256 (wave per row) -------------
__global__ __launch_bounds__(256) void ffn2ln_kernel(
    const float* __restrict__ hid, const float* __restrict__ Y3,
    const float* __restrict__ W2, const float* __restrict__ b2,
    const float* __restrict__ g, const float* __restrict__ bb, float* __restrict__ xout)
{
    __shared__ float sh[4][32];
    const int wv = threadIdx.x >> 6, lane = threadIdx.x & 63;
    const int row = blockIdx.x * 4 + wv;
    if (lane < 32) sh[wv][lane] = hid[row * 32 + lane];
    __syncthreads();
    float acc0 = b2[lane], acc1 = b2[lane + 64];
#pragma unroll 8
    for (int k = 0; k < 32; ++k) {
        const float hv = sh[wv][k];
        acc0 = fmaf(hv, W2[k * 128 + lane], acc0);
        acc1 = fmaf(hv, W2[k * 128 + lane + 64], acc1);
    }
    const float v0 = acc0 + Y3[row * 128 + lane];
    const float v1 = acc1 + Y3[row * 128 + lane + 64];
    float sum = v0 + v1, sq = v0 * v0 + v1 * v1;
#pragma unroll
    for (int o = 32; o >= 1; o >>= 1) { sum += __shfl_xor(sum, o); sq += __shfl_xor(sq, o); }
    const float mean = sum * (1.f / 128.f);
    const float var = sq * (1.f / 128.f) - mean * mean;
    const float rs = rsqrtf(var + 1e-5f);
    xout[row * 128 + lane]      = (v0 - mean) * rs * g[lane] + bb[lane];
    xout[row * 128 + lane + 64] = (v1 - mean) * rs * g[lane + 64] + bb[lane + 64];
}

// ================= head =================
__global__ __launch_bounds__(256) void head_prep_kernel(
    const float* __restrict__ psi, const float* __restrict__ W_q, const float* __restrict__ W_k,
    const float* __restrict__ f_b, const float* __restrict__ hmix, const float* __restrict__ attn_a,
    float* __restrict__ mixb, float* __restrict__ alphab, float* __restrict__ bft,
    float* __restrict__ Qb, float* __restrict__ Kb)
{
    const int tid = threadIdx.x;
    const float m0 = hmix[0], m1 = hmix[1], m2 = hmix[2], m3 = hmix[3];
    const float mx = fmaxf(fmaxf(m0, m1), fmaxf(m2, m3));
    const float e0 = __expf(m0 - mx), e1 = __expf(m1 - mx), e2 = __expf(m2 - mx), e3 = __expf(m3 - mx);
    const float inv = 1.f / (e0 + e1 + e2 + e3);
    float mixv[4] = {e0 * inv, e1 * inv, e2 * inv, e3 * inv};
    if (tid < 4) mixb[tid] = mixv[tid];
    if (tid == 4) alphab[0] = sigf(attn_a[0]);
    if (tid < 128) {
        float s = 0.f;
        for (int h = 0; h < 4; ++h) {
            float t = 0.f;
            for (int d = 0; d < 10; ++d) t = fmaf(psi[tid * 10 + d], f_b[h * 10 + d], t);
            s = fmaf(mixv[h], t, s);
        }
        bft[tid] = s;
    }
    for (int idx = tid; idx < 5120; idx += 256) {
        const int n = idx / 40, rem = idx - n * 40, h = rem / 10, d = rem - h * 10;
        float q = 0.f, kk = 0.f;
        for (int d0 = 0; d0 < 10; ++d0) {
            const float pv = psi[n * 10 + d0];
            q = fmaf(pv, W_q[(d0 * 4 + h) * 10 + d], q);
            kk = fmaf(pv, W_k[(d0 * 4 + h) * 10 + d], kk);
        }
        Qb[idx] = q; Kb[idx] = kk;
    }
}

__global__ __launch_bounds__(256) void head_qk_kernel(
    const float* __restrict__ psi, const float* __restrict__ psis,
    const float* __restrict__ Qb, const float* __restrict__ Kb,
    float* __restrict__ gbuf, float* __restrict__ qkbuf)
{
    const int idx = blockIdx.x * 256 + threadIdx.x;  // 16384
    const int n = idx >> 7, mcol = idx & 127;
    float d2 = 0.f;
#pragma unroll
    for (int d = 0; d < 10; ++d) { const float df = psi[n * 10 + d] - psi[mcol * 10 + d]; d2 = fmaf(df, df, d2); }
    gbuf[idx] = __expf(-psis[0] * d2);
#pragma unroll
    for (int h = 0; h < 4; ++h) {
        float qq = 0.f;
#pragma unroll
        for (int d = 0; d < 10; ++d) qq = fmaf(Qb[n * 40 + h * 10 + d], Kb[mcol * 40 + h * 10 + d], qq);
        qkbuf[h * 16384 + idx] = qq * 0.3162277660168379332f;  // 1/sqrt(10)
    }
}

__global__ __launch_bounds__(128) void head_aeff_kernel(
    const float* __restrict__ gbuf, const float* __restrict__ qkbuf, const float* __restrict__ alphab,
    float* __restrict__ Aeff, float* __restrict__ StT)
{
    __shared__ float red[128];
    const int h = blockIdx.x >> 7, n = blockIdx.x & 127, mcol = threadIdx.x;
    const float gv = gbuf[n * 128 + mcol];
    const float qv = qkbuf[h * 16384 + n * 128 + mcol];
    float r;
    // max(g)
    red[mcol] = gv; __syncthreads();
    for (int s = 64; s >= 1; s >>= 1) { if (mcol < s) red[mcol] = fmaxf(red[mcol], red[mcol + s]); __syncthreads(); }
    r = red[0]; __syncthreads();
    const float eg = __expf(gv - r);
    red[mcol] = eg; __syncthreads();
    for (int s = 64; s >= 1; s >>= 1) { if (mcol < s) red[mcol] += red[mcol + s]; __syncthreads(); }
    const float gsum = red[0]; __syncthreads();
    red[mcol] = qv; __syncthreads();
    for (int s = 64; s >= 1; s >>= 1) { if (mcol < s) red[mcol] = fmaxf(red[mcol], red[mcol + s]); __syncthreads(); }
    r = red[0]; __syncthreads();
    const float eq = __expf(qv - r);
    red[mcol] = eq; __syncthreads();
    for (int s = 64; s >= 1; s >>= 1) { if (mcol < s) red[mcol] += red[mcol + s]; __syncthreads(); }
    const float qsum = red[0];
    const float al = alphab[0];
    const float aeff = al * (eg / gsum) + (1.f - al) * (eq / qsum);
    Aeff[h * 16384 + n * 128 + mcol] = aeff;
    StT[((h * 4 + 1) * 128 + mcol) * 128 + n] = aeff;           // S1^T
    StT[((h * 4 + 0) * 128 + mcol) * 128 + n] = (mcol == n) ? 1.f : 0.f;  // I
}

// S_kk = 2*A@S_{kk-1} - S_{kk-2}. grid 256 (4h x 64), block 256.
__global__ __launch_bounds__(256) void head_cheb_kernel(
    const float* __restrict__ Aeff, float* __restrict__ StT, int kk)
{
    const int h = blockIdx.x >> 6;
    const int m0 = ((blockIdx.x & 63) << 1) + (threadIdx.x >> 7);
    const int n = threadIdx.x & 127;
    const float* Ar = Aeff + h * 16384 + n * 128;
    const float* Sp = StT + ((h * 4 + kk - 1) * 128 + m0) * 128;
    float acc = 0.f;
#pragma unroll 8
    for (int p = 0; p < 128; ++p) acc = fmaf(Ar[p], Sp[p], acc);
    const float s2 = StT[((h * 4 + kk - 2) * 128 + m0) * 128 + n];
    StT[((h * 4 + kk) * 128 + m0) * 128 + n] = 2.f * acc - s2;
}

// Wf[h][k][l][n] = sum_d psi[n,d]*F_w[h,d,k,l]. grid 4096, block 256.
__global__ __launch_bounds__(256) void head_wf_kernel(
    const float* __restrict__ psi, const float* __restrict__ F_w, float* __restrict__ WfT)
{
    const int idx = blockIdx.x * 256 + threadIdx.x;  // 2^20
    const int n = idx & 127, l = (idx >> 7) & 511, k = (idx >> 16) & 3, h = idx >> 18;
    float acc = 0.f;
#pragma unroll
    for (int d = 0; d < 10; ++d)
        acc = fmaf(psi[n * 10 + d], F_w[((h * 10 + d) * 4 + k) * 512 + l], acc);
    WfT[idx] = acc;
}

// V[l][m][n] = sum_h mix_h sum_k S^T[h,k,m,n]*Wf[h,k,l,n]. grid 32768, block 256.
__global__ __launch_bounds__(256) void head_v_kernel(
    const float* __restrict__ StT, const float* __restrict__ WfT, const float* __restrict__ mixb,
    float* __restrict__ V)
{
    const int idx = blockIdx.x * 256 + threadIdx.x;  // 2^23
    const int n = idx & 127, mcol = (idx >> 7) & 127, l = idx >> 14;
    float acc = 0.f;
#pragma unroll
    for (int h = 0; h < 4; ++h) {
        const float mx = mixb[h];
#pragma unroll
        for (int k = 0; k < 4; ++k) {
            const float sv = StT[((h * 4 + k) * 128 + mcol) * 128 + n];
            const float wv = WfT[((h * 4 + k) * 512 + l) * 128 + n];
            acc = fmaf(mx * sv, wv, acc);
        }
    }
    V[idx] = acc;
}

// split-K contraction: partial[l][b][n] = sum_m x[b,l,m]*V[l,m,n]. grid 512, block 128.
__global__ __launch_bounds__(128) void head_ctr_kernel(
    const float* __restrict__ Xf, const float* __restrict__ V, float* __restrict__ partial)
{
    __shared__ float sx[32][128];
    const int l = blockIdx.x, tid = threadIdx.x;
    for (int q = tid; q < 4096; q += 128) {
        const int b = q >> 7, mm = q & 127;
        sx[b][mm] = Xf[(b * 512 + l) * 128 + mm];
    }
    __syncthreads();
    float acc[32];
#pragma unroll
    for (int b = 0; b < 32; ++b) acc[b] = 0.f;
    for (int mm = 0; mm < 128; ++mm) {
        const float v = V[(l * 128 + mm) * 128 + tid];
#pragma unroll
        for (int b = 0; b < 32; ++b) acc[b] = fmaf(sx[b][mm], v, acc[b]);
    }
#pragma unroll
    for (int b = 0; b < 32; ++b) partial[(blockIdx.x * 32 + b) * 128 + tid] = acc[b];
}

// reduce partials, add bias, compute pred, zero log_var. grid 32, block 128.
__global__ __launch_bounds__(128) void head_out_kernel(
    const float* __restrict__ partial, const float* __restrict__ bft,
    const float* __restrict__ head_w, const float* __restrict__ head_b, float* __restrict__ out)
{
    __shared__ float red[128];
    const int b = blockIdx.x, n = threadIdx.x;
    float s = bft[n];
    for (int c = 0; c < 512; ++c) s += partial[(c * 32 + b) * 128 + n];
    red[n] = s * head_w[n];
    __syncthreads();
    for (int st = 64; st >= 1; st >>= 1) { if (n < st) red[n] += red[n + st]; __syncthreads(); }
    if (n == 0) out[b] = red[0] + head_b[0];
    out[32 + b * 128 + n] = 0.f;   // log_var = zeros
}

extern "C" void kernel_launch(void* const* d_in, const int* in_sizes, int n_in,
                              void* d_out, int out_size, void* d_ws, size_t ws_size,
                              hipStream_t stream) {
    const float* x_in    = (const float*)d_in[0];
    const float* in_w    = (const float*)d_in[1];
    const float* conv_w  = (const float*)d_in[2];
    const float* conv_b  = (const float*)d_in[3];
    const float* xproj_w = (const float*)d_in[4];
    const float* dt_w    = (const float*)d_in[5];
    const float* dt_b    = (const float*)d_in[6];
    const float* Alog    = (const float*)d_in[7];
    const float* Dp      = (const float*)d_in[8];
    const float* out_w   = (const float*)d_in[9];
    const float* ln1_g   = (const float*)d_in[10];
    const float* ln1_b   = (const float*)d_in[11];
    const float* ln2_g   = (const float*)d_in[12];
    const float* ln2_b   = (const float*)d_in[13];
    const float* ffn_w1  = (const float*)d_in[14];
    const float* ffn_b1  = (const float*)d_in[15];
    const float* ffn_w2  = (const float*)d_in[16];
    const float* ffn_b2  = (const float*)d_in[17];
    const float* psi_emb = (const float*)d_in[18];
    const float* psi_s   = (const float*)d_in[19];
    const float* W_q     = (const float*)d_in[20];
    const float* W_k     = (const float*)d_in[21];
    const float* attn_a  = (const float*)d_in[22];
    const float* F_w     = (const float*)d_in[23];
    const float* f_b     = (const float*)d_in[24];
    const float* hmix    = (const float*)d_in[25];
    const float* head_w  = (const float*)d_in[26];
    const float* head_b  = (const float*)d_in[27];
    float* ws = (float*)d_ws;
    float* outp = (float*)d_out;
    // requires ws_size >= 76,021,760 bytes

    for (int i = 0; i < 3; ++i) {
        const float* xcur = (i == 0) ? x_in : (ws + OFF_X);
        const int mF = 2 * i, mB = 2 * i + 1;
        gemm_in2_kernel<<<1024, 256, 0, stream>>>(
            xcur, in_w + mF * 16384, in_w + mB * 16384, ws + OFF_XZF, ws + OFF_XZB);
        prep2_kernel<<<8192, 256, 0, stream>>>(
            ws + OFF_XZF, ws + OFF_XZB, conv_w, conv_b, xproj_w, dt_w, dt_b, i,
            ws + OFF_XPF, ws + OFF_XPB, ws + OFF_XDF, ws + OFF_XDB, ws + OFF_DLF, ws + OFF_DLB);
        scan2_kernel<<<1024, 256, 0, stream>>>(
            ws + OFF_XDF, ws + OFF_XDB, ws + OFF_DLF, ws + OFF_DLB, ws + OFF_XPF, ws + OFF_XPB,
            Alog + mF * 4096, Alog + mB * 4096, ws + OFF_YSF, ws + OFF_YSB);
        gate2_kernel<<<8192, 256, 0, stream>>>(
            ws + OFF_YSF, ws + OFF_YSB, ws + OFF_XPF, ws + OFF_XPB, ws + OFF_XZF, ws + OFF_XZB,
            Dp, i, ws + OFF_YGF, ws + OFF_YGB);
        outproj2_kernel<<<2048, 256, 0, stream>>>(
            ws + OFF_YGF, ws + OFF_YGB, out_w, i, ws + OFF_Y1, ws + OFF_Y2);
        ln3_kernel<<<4096, 256, 0, stream>>>(
            xcur, ws + OFF_Y1, ws + OFF_Y2, ln1_g + i * 128, ln1_b + i * 128, ws + OFF_Y3);
        ffn1_kernel<<<2048, 256, 0, stream>>>(
            ws + OFF_Y3, ffn_w1 + i * 4096, ffn_b1 + i * 32, ws + OFF_HID);
        ffn2ln_kernel<<<4096, 256, 0, stream>>>(
            ws + OFF_HID, ws + OFF_Y3, ffn_w2 + i * 4096, ffn_b2 + i * 128,
            ln2_g + i * 128, ln2_b + i * 128, ws + OFF_X);
    }
    // head
    head_prep_kernel<<<1, 256, 0, stream>>>(
        psi_emb, W_q, W_k, f_b, hmix, attn_a,
        ws + OFF_MIX, ws + OFF_ALPH, ws + OFF_BFT, ws + OFF_QB, ws + OFF_KB);
    head_qk_kernel<<<64, 256, 0, stream>>>(
        psi_emb, psi_s, ws + OFF_QB, ws + OFF_KB, ws + OFF_GB, ws + OFF_QKB);
    head_aeff_kernel<<<512, 128, 0, stream>>>(
        ws + OFF_GB, ws + OFF_QKB, ws + OFF_ALPH, ws + OFF_AEFF, ws + OFF_STT);
    head_cheb_kernel<<<256, 256, 0, stream>>>(ws + OFF_AEFF, ws + OFF_STT, 2);
    head_cheb_kernel<<<256, 256, 0, stream>>>(ws + OFF_AEFF, ws + OFF_STT, 3);
    head_wf_kernel<<<4096, 256, 0, stream>>>(psi_emb, F_w, ws + OFF_WFT);
    head_v_kernel<<<32768, 256, 0, stream>>>(ws + OFF_STT, ws + OFF_WFT, ws + OFF_MIX, ws + OFF_V);
    head_ctr_kernel<<<512, 128, 0, stream>>>(ws + OFF_X, ws + OFF_V, ws + OFF_PART);
    head_out_kernel<<<32, 128, 0, stream>>>(
        ws + OFF_PART, ws + OFF_BFT, head_w, head_b, outp);
}

// Round 2
// 766.959 us; speedup vs baseline: 1.0531x; 1.0531x over previous
//
#include <hip/hip_runtime.h>
#include <hip/hip_bf16.h>

// MAMBA_BayesMAGAC: B=32, L=512, D=128, E=64, HS=64, DTR=4, U=32, R=3, K=3, DE=10, NH=4
// Round 2: scan v2 (packed dl/du + stride-512B B/C + unrolled imm offsets),
// retiled in-proj GEMM, fused outproj+LN1, fused FFN+LN2.

#define B_ 32
#define L_ 512
#define D_ 128
#define E_ 64
#define HS_ 64

// ---- workspace offsets (floats) ----
#define OFF_X     0u          // 2,097,152  x [b][l][128]
#define OFF_XZF   2097152u    // 2,097,152  xz fwd [b][l][128]
#define OFF_XZB   4194304u
#define OFF_XPF   6291456u    // 1,048,576  xp [b][l][64]
#define OFF_XPB   7340032u
#define OFF_PKF   8388608u    // 2,097,152  (dl,du) [b][l][64][2]
#define OFF_PKB   10485760u
#define OFF_XBCF  12582912u   // 2,097,152  (B,C) [b][l][128]
#define OFF_XBCB  14680064u
#define OFF_YSF   16777216u   // 1,048,576  scan y [b][e][l]
#define OFF_YSB   17825792u   // end 18,874,368 floats = 75.5 MB
// reuse (liveness-checked):
#define OFF_YGF   8388608u    // over PKF (dead after scan)
#define OFF_YGB   9437184u
#define OFF_Y3    16777216u   // over YSF+YSB (dead after gate)
// head phase (only OFF_X live):
#define OFF_V     2097152u    // 8,388,608  V [l][m][n]
#define OFF_WFT   10485760u   // 1,048,576  Wf [h][k][l][n]
#define OFF_STT   11534336u   // 262,144    S^T [h][k][m][n]
#define OFF_AEFF  11796480u   // 65,536
#define OFF_GB    11862016u   // 16,384
#define OFF_QKB   11878400u   // 65,536
#define OFF_QB    11943936u   // 5,120
#define OFF_KB    11949056u   // 5,120
#define OFF_MIX   11954176u   // 4
#define OFF_ALPH  11954180u   // 1
#define OFF_BFT   11954184u   // 128
#define OFF_PART  12582912u   // 2,097,152  partial [512][32][128]

__device__ __forceinline__ float sigf(float x) { return 1.f / (1.f + __expf(-x)); }

// ---------------- in-projection: xz = x @ in_w (both dirs), 32 rows/block ----------------
// grid 512, block 256. Wave: (dir, col-half); lane = (r4, c16); acc 8 rows x 4 cols.
__global__ __launch_bounds__(256) void gemm_in2_kernel(
    const float* __restrict__ X, const float* __restrict__ WF, const float* __restrict__ WB,
    float* __restrict__ xzF, float* __restrict__ xzB)
{
    __shared__ float sxT[128][36];    // transposed x tile, padded
    __shared__ float sw[2][16][128];
    const int tid = threadIdx.x;
    const int r0 = blockIdx.x * 32;
    for (int q = tid; q < 32 * 128; q += 256) {
        const int r = q >> 7, k = q & 127;
        sxT[k][r] = X[(r0 + r) * 128 + k];
    }
    const int wv = tid >> 6, lane = tid & 63;
    const int d = wv >> 1, ch = wv & 1;
    const int r4 = lane >> 4, c16 = lane & 15;
    float4 acc[8];
#pragma unroll
    for (int j = 0; j < 8; ++j) acc[j] = float4{0.f, 0.f, 0.f, 0.f};
    for (int ko = 0; ko < 128; ko += 16) {
        __syncthreads();
        for (int q = tid; q < 2 * 16 * 128; q += 256) {
            const int dd = q >> 11, kk = (q >> 7) & 15, c = q & 127;
            sw[dd][kk][c] = (dd ? WB : WF)[(ko + kk) * 128 + c];
        }
        __syncthreads();
#pragma unroll
        for (int kk = 0; kk < 16; ++kk) {
            const float4 w4 = *(const float4*)&sw[d][kk][ch * 64 + c16 * 4];
            const float4 xa = *(const float4*)&sxT[ko + kk][r4 * 8];
            const float4 xb = *(const float4*)&sxT[ko + kk][r4 * 8 + 4];
            const float xs[8] = {xa.x, xa.y, xa.z, xa.w, xb.x, xb.y, xb.z, xb.w};
#pragma unroll
            for (int j = 0; j < 8; ++j) {
                acc[j].x = fmaf(xs[j], w4.x, acc[j].x);
                acc[j].y = fmaf(xs[j], w4.y, acc[j].y);
                acc[j].z = fmaf(xs[j], w4.z, acc[j].z);
                acc[j].w = fmaf(xs[j], w4.w, acc[j].w);
            }
        }
    }
    float* xz = d ? xzB : xzF;
#pragma unroll
    for (int j = 0; j < 8; ++j) {
        *(float4*)&xz[(r0 + r4 * 8 + j) * 128 + ch * 64 + c16 * 4] = acc[j];
    }
}

// ------------- conv + silu + xproj + delta, both dirs. grid 8192, block 256 -------------
// outputs: xp, xbc[row][128] = (B|C), pk[row][e] = float2(dl, dl*u)
__global__ __launch_bounds__(256) void prep2_kernel(
    const float* __restrict__ xzF_, const float* __restrict__ xzB_,
    const float* __restrict__ conv_w, const float* __restrict__ conv_b,
    const float* __restrict__ xproj_w, const float* __restrict__ dt_w,
    const float* __restrict__ dt_b, int layer,
    float* __restrict__ xpF_, float* __restrict__ xpB_,
    float* __restrict__ xbcF_, float* __restrict__ xbcB_,
    float* __restrict__ pkF_, float* __restrict__ pkB_)
{
    __shared__ float sW[64 * 132];
    __shared__ float sxp[4][64];
    __shared__ float sdl[4][4];
    const int tid = threadIdx.x, wv = tid >> 6, lane = tid & 63;
    const int wid = blockIdx.x * 4 + wv;          // 0..32767
    const int dir = wid >> 14;                    // block-uniform
    const int row = wid & 16383;
    const int b = row >> 9, l = row & 511;
    const int m = layer * 2 + dir;
    // stage xproj W (m block-uniform)
    const float* Wg = xproj_w + m * 8448;
    for (int q = tid; q < 8448; q += 256) sW[q] = Wg[q];
    const float* xz = dir ? xzB_ : xzF_;
    float* xp  = dir ? xpB_  : xpF_;
    float* xbc = dir ? xbcB_ : xbcF_;
    float* pkx = dir ? pkB_  : pkF_;
    // depthwise causal conv (on flipped seq for bwd), e = lane
    const float* cw = conv_w + m * 192 + lane * 3;
    const int l1 = dir ? l + 1 : l - 1;
    const int l2 = dir ? l + 2 : l - 2;
    float acc = conv_b[m * 64 + lane];
    const float x0 = xz[(b * 512 + l) * 128 + lane];
    const float x1 = (l1 >= 0 && l1 < 512) ? xz[(b * 512 + l1) * 128 + lane] : 0.f;
    const float x2 = (l2 >= 0 && l2 < 512) ? xz[(b * 512 + l2) * 128 + lane] : 0.f;
    acc += cw[0] * x2 + cw[1] * x1 + cw[2] * x0;
    const float u = acc * sigf(acc);   // silu
    xp[row * 64 + lane] = u;
    sxp[wv][lane] = u;
    __syncthreads();
    // xproj: cols 4+lane (B), 68+lane (C), lane&3 (delta-in)
    const int jdt = lane & 3;
    float aB = 0.f, aC = 0.f, adt = 0.f;
#pragma unroll 8
    for (int k = 0; k < 64; ++k) {
        const float xv = sxp[wv][k];
        aB  = fmaf(xv, sW[k * 132 + 4 + lane], aB);
        aC  = fmaf(xv, sW[k * 132 + 68 + lane], aC);
        adt = fmaf(xv, sW[k * 132 + jdt], adt);
    }
    xbc[row * 128 + lane]      = aB;
    xbc[row * 128 + 64 + lane] = aC;
    if (lane < 4) sdl[wv][lane] = adt;
    __syncthreads();
    // delta = softplus(dtin @ dt_w + dt_b)
    float dpre = dt_b[m * 64 + lane];
    const float* dw = dt_w + m * 256;
#pragma unroll
    for (int r4 = 0; r4 < 4; ++r4) dpre = fmaf(sdl[wv][r4], dw[r4 * 64 + lane], dpre);
    const float dlt = (dpre > 20.f) ? dpre : log1pf(__expf(dpre));
    ((float2*)pkx)[row * 64 + lane] = float2{dlt, dlt * u};
}

// ------------- selective scan v2. grid 1024, block 256 (4 waves of same (b,dir)) -------------
__global__ __launch_bounds__(256, 4) void scan2_kernel(
    const float* __restrict__ xbcF, const float* __restrict__ xbcB,
    const float* __restrict__ pkF, const float* __restrict__ pkB,
    const float* __restrict__ AF, const float* __restrict__ AB,
    float* __restrict__ ysF, float* __restrict__ ysB)
{
    __shared__ float tile[4][32 * 65];
    const int wv = threadIdx.x >> 6, lane = threadIdx.x & 63;
    const int wid = blockIdx.x * 4 + wv;          // 0..4095
    const int dir = wid >> 11;                    // block-uniform
    const int be = wid & 2047;
    const int b = be >> 6, e = be & 63;
    const float* xbc = dir ? xbcB : xbcF;
    const float* pk  = dir ? pkB  : pkF;
    const float* Aw  = dir ? AB   : AF;
    float* ys = dir ? ysB : ysF;
    const float a = -__expf(Aw[e * 64 + lane]);   // A[e][n], n = lane
    float s = 0.f;
    float* tl = tile[wv];
    const int row0 = b * 512 + (dir ? 511 : 0);
    float* yrow = ys + (b * 64 + e) * 512;

#define SCAN_STEP(TT, OFS)                                    \
    {                                                         \
        const float Bn  = xr[(OFS) + lane];                   \
        const float Cn  = xr[(OFS) + 64 + lane];              \
        const float dlv = pk[pkoff + (OFS)];                  \
        const float duv = pk[pkoff + (OFS) + 1];              \
        const float dA  = __expf(dlv * a);                    \
        s = fmaf(dA, s, duv * Bn);                            \
        tl[(TT) * 65 + lane] = s * Cn;                        \
    }

    for (int t0 = 0; t0 < 512; t0 += 32) {
        const int rbase = dir ? (row0 - t0) : (row0 + t0);
        const float* xr = xbc + (size_t)rbase * 128;
        const int pkoff = __builtin_amdgcn_readfirstlane(rbase * 128 + e * 2);
        if (dir == 0) {
            for (int sub = 0; sub < 4; ++sub) {
                const int tb = sub * 8;
#pragma unroll
                for (int t2 = 0; t2 < 8; ++t2) { const int tt = tb + t2; SCAN_STEP(tt, tt * 128) }
            }
        } else {
            for (int sub = 0; sub < 4; ++sub) {
                const int tb = sub * 8;
#pragma unroll
                for (int t2 = 0; t2 < 8; ++t2) { const int tt = tb + t2; SCAN_STEP(tt, -(tt * 128)) }
            }
        }
        __syncthreads();
        const int tr = lane & 31, hf = lane >> 5;
        float p = 0.f;
#pragma unroll
        for (int j = 0; j < 32; ++j) p += tl[tr * 65 + hf * 32 + j];
        p += __shfl_xor(p, 32);
        if (lane < 32) {
            const int l = dir ? (511 - (t0 + tr)) : (t0 + tr);
            yrow[l] = p;
        }
        __syncthreads();
    }
#undef SCAN_STEP
}

// ------------- gate: yg = (ys + xp*D) * sigmoid(res). grid 8192, block 256 -------------
__global__ __launch_bounds__(256) void gate2_kernel(
    const float* __restrict__ ysF_, const float* __restrict__ ysB_,
    const float* __restrict__ xpF_, const float* __restrict__ xpB_,
    const float* __restrict__ xzF_, const float* __restrict__ xzB_,
    const float* __restrict__ Dp, int layer,
    float* __restrict__ ygF_, float* __restrict__ ygB_)
{
    const int idx = blockIdx.x * 256 + threadIdx.x;  // < 2*2^20
    const int dir = idx >> 20;
    const int r = idx & 1048575;
    const int e = r & 63, bl = r >> 6;
    const int b = bl >> 9, l = bl & 511;
    const float* ys = dir ? ysB_ : ysF_;
    const float* xp = dir ? xpB_ : xpF_;
    const float* xz = dir ? xzB_ : xzF_;
    float* yg = dir ? ygB_ : ygF_;
    const float dv = Dp[(layer * 2 + dir) * 64 + e];
    const float y = ys[(b * 64 + e) * 512 + l];
    const float u = xp[bl * 64 + e];
    const float res = xz[bl * 128 + 64 + e];
    yg[bl * 64 + e] = (y + u * dv) * sigf(res);
}

// ------------- out-proj (both dirs as K=128 GEMM) + residual + LN1 -> Y3 -------------
// grid 1024, block 256 (16 rows).
__global__ __launch_bounds__(256) void opln_kernel(
    const float* __restrict__ ygF, const float* __restrict__ ygB,
    const float* __restrict__ Xc, const float* __restrict__ out_w, int layer,
    const float* __restrict__ g, const float* __restrict__ bb,
    float* __restrict__ Y3)
{
    __shared__ float sy[16][128];   // [row][ygF|ygB]
    __shared__ float sw[32][128];
    const int tid = threadIdx.x;
    const int r0 = blockIdx.x * 16;
    for (int q = tid; q < 2048; q += 256) {
        const int r = q >> 7, c = q & 127;
        sy[r][c] = (c < 64) ? ygF[(r0 + r) * 64 + c] : ygB[(r0 + r) * 64 + (c - 64)];
    }
    const int wv = tid >> 6, lane = tid & 63;
    const float* WFp = out_w + (layer * 2) * 8192;
    const float* WBp = out_w + (layer * 2 + 1) * 8192;
    float acc[4][2];
#pragma unroll
    for (int r = 0; r < 4; ++r) { acc[r][0] = 0.f; acc[r][1] = 0.f; }
    for (int ko = 0; ko < 128; ko += 32) {
        __syncthreads();
        for (int q = tid; q < 4096; q += 256) {
            const int kk = q >> 7, c = q & 127;
            const int kg = ko + kk;
            sw[kk][c] = (kg < 64) ? WFp[kg * 128 + c] : WBp[(kg - 64) * 128 + c];
        }
        __syncthreads();
#pragma unroll
        for (int kk = 0; kk < 32; ++kk) {
            const float w0 = sw[kk][lane], w1 = sw[kk][lane + 64];
            const int kg = ko + kk;
#pragma unroll
            for (int r = 0; r < 4; ++r) {
                const float yv = sy[wv * 4 + r][kg];
                acc[r][0] = fmaf(yv, w0, acc[r][0]);
                acc[r][1] = fmaf(yv, w1, acc[r][1]);
            }
        }
    }
#pragma unroll
    for (int r = 0; r < 4; ++r) {
        const int row = r0 + wv * 4 + r;
        float v0 = acc[r][0] + Xc[row * 128 + lane];
        float v1 = acc[r][1] + Xc[row * 128 + lane + 64];
        float sum = v0 + v1, sq = v0 * v0 + v1 * v1;
#pragma unroll
        for (int o = 32; o >= 1; o >>= 1) { sum += __shfl_xor(sum, o); sq += __shfl_xor(sq, o); }
        const float mean = sum * (1.f / 128.f);
        const float var = sq * (1.f / 128.f) - mean * mean;
        const float rs = rsqrtf(var + 1e-5f);
        Y3[row * 128 + lane]      = (v0 - mean) * rs * g[lane] + bb[lane];
        Y3[row * 128 + lane + 64] = (v1 - mean) * rs * g[lane + 64] + bb[lane + 64];
    }
}

// ------------- FFN1 + FFN2 + residual + LN2 -> x. grid 1024, block 256 (16 rows) -------------
__global__ __launch_bounds__(256) void ffn_kernel(
    const float* __restrict__ Y3, const float* __restrict__ W1, const float* __restrict__ b1,
    const float* __restrict__ W2, const float* __restrict__ b2,
    const float* __restrict__ g, const float* __restrict__ bb, float* __restrict__ xout)
{
    __shared__ float sx[16][128];
    __shared__ float sw1[128][32];
    __shared__ float sh[16][32];
    __shared__ float sw2[32][128];
    const int tid = threadIdx.x;
    const int r0 = blockIdx.x * 16;
    for (int q = tid; q < 2048; q += 256) sx[q >> 7][q & 127] = Y3[r0 * 128 + q];
    for (int q = tid; q < 4096; q += 256) sw1[q >> 5][q & 31] = W1[q];
    for (int q = tid; q < 4096; q += 256) sw2[q >> 7][q & 127] = W2[q];
    __syncthreads();
    {
        const int r = tid >> 4, u = tid & 15;
        float h0 = b1[u], h1 = b1[u + 16];
#pragma unroll 8
        for (int k = 0; k < 128; ++k) {
            const float xv = sx[r][k];
            h0 = fmaf(xv, sw1[k][u], h0);
            h1 = fmaf(xv, sw1[k][u + 16], h1);
        }
        sh[r][u]      = fmaxf(h0, 0.f);
        sh[r][u + 16] = fmaxf(h1, 0.f);
    }
    __syncthreads();
    const int wv = tid >> 6, lane = tid & 63;
#pragma unroll
    for (int r = 0; r < 4; ++r) {
        const int rl = wv * 4 + r;
        float a0 = b2[lane], a1 = b2[lane + 64];
#pragma unroll 8
        for (int k = 0; k < 32; ++k) {
            const float hv = sh[rl][k];
            a0 = fmaf(hv, sw2[k][lane], a0);
            a1 = fmaf(hv, sw2[k][lane + 64], a1);
        }
        const float v0 = a0 + sx[rl][lane];
        const float v1 = a1 + sx[rl][lane + 64];
        float sum = v0 + v1, sq = v0 * v0 + v1 * v1;
#pragma unroll
        for (int o = 32; o >= 1; o >>= 1) { sum += __shfl_xor(sum, o); sq += __shfl_xor(sq, o); }
        const float mean = sum * (1.f / 128.f);
        const float var = sq * (1.f / 128.f) - mean * mean;
        const float rs = rsqrtf(var + 1e-5f);
        const int row = r0 + rl;
        xout[row * 128 + lane]      = (v0 - mean) * rs * g[lane] + bb[lane];
        xout[row * 128 + lane + 64] = (v1 - mean) * rs * g[lane + 64] + bb[lane + 64];
    }
}

// ================= head (unchanged from round 1, passed) =================
__global__ __launch_bounds__(256) void head_prep_kernel(
    const float* __restrict__ psi, const float* __restrict__ W_q, const float* __restrict__ W_k,
    const float* __restrict__ f_b, const float* __restrict__ hmix, const float* __restrict__ attn_a,
    float* __restrict__ mixb, float* __restrict__ alphab, float* __restrict__ bft,
    float* __restrict__ Qb, float* __restrict__ Kb)
{
    const int tid = threadIdx.x;
    const float m0 = hmix[0], m1 = hmix[1], m2 = hmix[2], m3 = hmix[3];
    const float mx = fmaxf(fmaxf(m0, m1), fmaxf(m2, m3));
    const float e0 = __expf(m0 - mx), e1 = __expf(m1 - mx), e2 = __expf(m2 - mx), e3 = __expf(m3 - mx);
    const float inv = 1.f / (e0 + e1 + e2 + e3);
    float mixv[4] = {e0 * inv, e1 * inv, e2 * inv, e3 * inv};
    if (tid < 4) mixb[tid] = mixv[tid];
    if (tid == 4) alphab[0] = sigf(attn_a[0]);
    if (tid < 128) {
        float s = 0.f;
        for (int h = 0; h < 4; ++h) {
            float t = 0.f;
            for (int d = 0; d < 10; ++d) t = fmaf(psi[tid * 10 + d], f_b[h * 10 + d], t);
            s = fmaf(mixv[h], t, s);
        }
        bft[tid] = s;
    }
    for (int idx = tid; idx < 5120; idx += 256) {
        const int n = idx / 40, rem = idx - n * 40, h = rem / 10, d = rem - h * 10;
        float q = 0.f, kk = 0.f;
        for (int d0 = 0; d0 < 10; ++d0) {
            const float pv = psi[n * 10 + d0];
            q = fmaf(pv, W_q[(d0 * 4 + h) * 10 + d], q);
            kk = fmaf(pv, W_k[(d0 * 4 + h) * 10 + d], kk);
        }
        Qb[idx] = q; Kb[idx] = kk;
    }
}

__global__ __launch_bounds__(256) void head_qk_kernel(
    const float* __restrict__ psi, const float* __restrict__ psis,
    const float* __restrict__ Qb, const float* __restrict__ Kb,
    float* __restrict__ gbuf, float* __restrict__ qkbuf)
{
    const int idx = blockIdx.x * 256 + threadIdx.x;  // 16384
    const int n = idx >> 7, mcol = idx & 127;
    float d2 = 0.f;
#pragma unroll
    for (int d = 0; d < 10; ++d) { const float df = psi[n * 10 + d] - psi[mcol * 10 + d]; d2 = fmaf(df, df, d2); }
    gbuf[idx] = __expf(-psis[0] * d2);
#pragma unroll
    for (int h = 0; h < 4; ++h) {
        float qq = 0.f;
#pragma unroll
        for (int d = 0; d < 10; ++d) qq = fmaf(Qb[n * 40 + h * 10 + d], Kb[mcol * 40 + h * 10 + d], qq);
        qkbuf[h * 16384 + idx] = qq * 0.3162277660168379332f;  // 1/sqrt(10)
    }
}

__global__ __launch_bounds__(128) void head_aeff_kernel(
    const float* __restrict__ gbuf, const float* __restrict__ qkbuf, const float* __restrict__ alphab,
    float* __restrict__ Aeff, float* __restrict__ StT)
{
    __shared__ float red[128];
    const int h = blockIdx.x >> 7, n = blockIdx.x & 127, mcol = threadIdx.x;
    const float gv = gbuf[n * 128 + mcol];
    const float qv = qkbuf[h * 16384 + n * 128 + mcol];
    float r;
    red[mcol] = gv; __syncthreads();
    for (int s = 64; s >= 1; s >>= 1) { if (mcol < s) red[mcol] = fmaxf(red[mcol], red[mcol + s]); __syncthreads(); }
    r = red[0]; __syncthreads();
    const float eg = __expf(gv - r);
    red[mcol] = eg; __syncthreads();
    for (int s = 64; s >= 1; s >>= 1) { if (mcol < s) red[mcol] += red[mcol + s]; __syncthreads(); }
    const float gsum = red[0]; __syncthreads();
    red[mcol] = qv; __syncthreads();
    for (int s = 64; s >= 1; s >>= 1) { if (mcol < s) red[mcol] = fmaxf(red[mcol], red[mcol + s]); __syncthreads(); }
    r = red[0]; __syncthreads();
    const float eq = __expf(qv - r);
    red[mcol] = eq; __syncthreads();
    for (int s = 64; s >= 1; s >>= 1) { if (mcol < s) red[mcol] += red[mcol + s]; __syncthreads(); }
    const float qsum = red[0];
    const float al = alphab[0];
    const float aeff = al * (eg / gsum) + (1.f - al) * (eq / qsum);
    Aeff[h * 16384 + n * 128 + mcol] = aeff;
    StT[((h * 4 + 1) * 128 + mcol) * 128 + n] = aeff;
    StT[((h * 4 + 0) * 128 + mcol) * 128 + n] = (mcol == n) ? 1.f : 0.f;
}

__global__ __launch_bounds__(256) void head_cheb_kernel(
    const float* __restrict__ Aeff, float* __restrict__ StT, int kk)
{
    const int h = blockIdx.x >> 6;
    const int m0 = ((blockIdx.x & 63) << 1) + (threadIdx.x >> 7);
    const int n = threadIdx.x & 127;
    const float* Ar = Aeff + h * 16384 + n * 128;
    const float* Sp = StT + ((h * 4 + kk - 1) * 128 + m0) * 128;
    float acc = 0.f;
#pragma unroll 8
    for (int p = 0; p < 128; ++p) acc = fmaf(Ar[p], Sp[p], acc);
    const float s2 = StT[((h * 4 + kk - 2) * 128 + m0) * 128 + n];
    StT[((h * 4 + kk) * 128 + m0) * 128 + n] = 2.f * acc - s2;
}

__global__ __launch_bounds__(256) void head_wf_kernel(
    const float* __restrict__ psi, const float* __restrict__ F_w, float* __restrict__ WfT)
{
    const int idx = blockIdx.x * 256 + threadIdx.x;  // 2^20
    const int n = idx & 127, l = (idx >> 7) & 511, k = (idx >> 16) & 3, h = idx >> 18;
    float acc = 0.f;
#pragma unroll
    for (int d = 0; d < 10; ++d)
        acc = fmaf(psi[n * 10 + d], F_w[((h * 10 + d) * 4 + k) * 512 + l], acc);
    WfT[idx] = acc;
}

__global__ __launch_bounds__(256) void head_v_kernel(
    const float* __restrict__ StT, const float* __restrict__ WfT, const float* __restrict__ mixb,
    float* __restrict__ V)
{
    const int idx = blockIdx.x * 256 + threadIdx.x;  // 2^23
    const int n = idx & 127, mcol = (idx >> 7) & 127, l = idx >> 14;
    float acc = 0.f;
#pragma unroll
    for (int h = 0; h < 4; ++h) {
        const float mx = mixb[h];
#pragma unroll
        for (int k = 0; k < 4; ++k) {
            const float sv = StT[((h * 4 + k) * 128 + mcol) * 128 + n];
            const float wv = WfT[((h * 4 + k) * 512 + l) * 128 + n];
            acc = fmaf(mx * sv, wv, acc);
        }
    }
    V[idx] = acc;
}

__global__ __launch_bounds__(128) void head_ctr_kernel(
    const float* __restrict__ Xf, const float* __restrict__ V, float* __restrict__ partial)
{
    __shared__ float sx[32][128];
    const int l = blockIdx.x, tid = threadIdx.x;
    for (int q = tid; q < 4096; q += 128) {
        const int b = q >> 7, mm = q & 127;
        sx[b][mm] = Xf[(b * 512 + l) * 128 + mm];
    }
    __syncthreads();
    float acc[32];
#pragma unroll
    for (int b = 0; b < 32; ++b) acc[b] = 0.f;
    for (int mm = 0; mm < 128; ++mm) {
        const float v = V[(l * 128 + mm) * 128 + tid];
#pragma unroll
        for (int b = 0; b < 32; ++b) acc[b] = fmaf(sx[b][mm], v, acc[b]);
    }
#pragma unroll
    for (int b = 0; b < 32; ++b) partial[(blockIdx.x * 32 + b) * 128 + tid] = acc[b];
}

__global__ __launch_bounds__(128) void head_out_kernel(
    const float* __restrict__ partial, const float* __restrict__ bft,
    const float* __restrict__ head_w, const float* __restrict__ head_b, float* __restrict__ out)
{
    __shared__ float red[128];
    const int b = blockIdx.x, n = threadIdx.x;
    float s = bft[n];
    for (int c = 0; c < 512; ++c) s += partial[(c * 32 + b) * 128 + n];
    red[n] = s * head_w[n];
    __syncthreads();
    for (int st = 64; st >= 1; st >>= 1) { if (n < st) red[n] += red[n + st]; __syncthreads(); }
    if (n == 0) out[b] = red[0] + head_b[0];
    out[32 + b * 128 + n] = 0.f;   // log_var = zeros
}

extern "C" void kernel_launch(void* const* d_in, const int* in_sizes, int n_in,
                              void* d_out, int out_size, void* d_ws, size_t ws_size,
                              hipStream_t stream) {
    const float* x_in    = (const float*)d_in[0];
    const float* in_w    = (const float*)d_in[1];
    const float* conv_w  = (const float*)d_in[2];
    const float* conv_b  = (const float*)d_in[3];
    const float* xproj_w = (const float*)d_in[4];
    const float* dt_w    = (const float*)d_in[5];
    const float* dt_b    = (const float*)d_in[6];
    const float* Alog    = (const float*)d_in[7];
    const float* Dp      = (const float*)d_in[8];
    const float* out_w   = (const float*)d_in[9];
    const float* ln1_g   = (const float*)d_in[10];
    const float* ln1_b   = (const float*)d_in[11];
    const float* ln2_g   = (const float*)d_in[12];
    const float* ln2_b   = (const float*)d_in[13];
    const float* ffn_w1  = (const float*)d_in[14];
    const float* ffn_b1  = (const float*)d_in[15];
    const float* ffn_w2  = (const float*)d_in[16];
    const float* ffn_b2  = (const float*)d_in[17];
    const float* psi_emb = (const float*)d_in[18];
    const float* psi_s   = (const float*)d_in[19];
    const float* W_q     = (const float*)d_in[20];
    const float* W_k     = (const float*)d_in[21];
    const float* attn_a  = (const float*)d_in[22];
    const float* F_w     = (const float*)d_in[23];
    const float* f_b     = (const float*)d_in[24];
    const float* hmix    = (const float*)d_in[25];
    const float* head_w  = (const float*)d_in[26];
    const float* head_b  = (const float*)d_in[27];
    float* ws = (float*)d_ws;
    float* outp = (float*)d_out;

    for (int i = 0; i < 3; ++i) {
        const float* xcur = (i == 0) ? x_in : (ws + OFF_X);
        const int mF = 2 * i, mB = 2 * i + 1;
        gemm_in2_kernel<<<512, 256, 0, stream>>>(
            xcur, in_w + mF * 16384, in_w + mB * 16384, ws + OFF_XZF, ws + OFF_XZB);
        prep2_kernel<<<8192, 256, 0, stream>>>(
            ws + OFF_XZF, ws + OFF_XZB, conv_w, conv_b, xproj_w, dt_w, dt_b, i,
            ws + OFF_XPF, ws + OFF_XPB, ws + OFF_XBCF, ws + OFF_XBCB, ws + OFF_PKF, ws + OFF_PKB);
        scan2_kernel<<<1024, 256, 0, stream>>>(
            ws + OFF_XBCF, ws + OFF_XBCB, ws + OFF_PKF, ws + OFF_PKB,
            Alog + mF * 4096, Alog + mB * 4096, ws + OFF_YSF, ws + OFF_YSB);
        gate2_kernel<<<8192, 256, 0, stream>>>(
            ws + OFF_YSF, ws + OFF_YSB, ws + OFF_XPF, ws + OFF_XPB, ws + OFF_XZF, ws + OFF_XZB,
            Dp, i, ws + OFF_YGF, ws + OFF_YGB);
        opln_kernel<<<1024, 256, 0, stream>>>(
            ws + OFF_YGF, ws + OFF_YGB, xcur, out_w, i,
            ln1_g + i * 128, ln1_b + i * 128, ws + OFF_Y3);
        ffn_kernel<<<1024, 256, 0, stream>>>(
            ws + OFF_Y3, ffn_w1 + i * 4096, ffn_b1 + i * 32,
            ffn_w2 + i * 4096, ffn_b2 + i * 128,
            ln2_g + i * 128, ln2_b + i * 128, ws + OFF_X);
    }
    // head
    head_prep_kernel<<<1, 256, 0, stream>>>(
        psi_emb, W_q, W_k, f_b, hmix, attn_a,
        ws + OFF_MIX, ws + OFF_ALPH, ws + OFF_BFT, ws + OFF_QB, ws + OFF_KB);
    head_qk_kernel<<<64, 256, 0, stream>>>(
        psi_emb, psi_s, ws + OFF_QB, ws + OFF_KB, ws + OFF_GB, ws + OFF_QKB);
    head_aeff_kernel<<<512, 128, 0, stream>>>(
        ws + OFF_GB, ws + OFF_QKB, ws + OFF_ALPH, ws + OFF_AEFF, ws + OFF_STT);
    head_cheb_kernel<<<256, 256, 0, stream>>>(ws + OFF_AEFF, ws + OFF_STT, 2);
    head_cheb_kernel<<<256, 256, 0, stream>>>(ws + OFF_AEFF, ws + OFF_STT, 3);
    head_wf_kernel<<<4096, 256, 0, stream>>>(psi_emb, F_w, ws + OFF_WFT);
    head_v_kernel<<<32768, 256, 0, stream>>>(ws + OFF_STT, ws + OFF_WFT, ws + OFF_MIX, ws + OFF_V);
    head_ctr_kernel<<<512, 128, 0, stream>>>(ws + OFF_X, ws + OFF_V, ws + OFF_PART);
    head_out_kernel<<<32, 128, 0, stream>>>(
        ws + OFF_PART, ws + OFF_BFT, head_w, head_b, outp);
}